// Round 7
// baseline (289.386 us; speedup 1.0000x reference)
//
#include <hip/hip_runtime.h>

// GCN layer: out = sum_r segment_sum(vals_r * inp[src_r], dst_r) @ W_r
// Round 7 (4-dispatch pipeline; in-block mini-CSR):
//   K1 setup:  inp->bf16, W->Wt[r][n][k] bf16, zero bucket counters.
//   K2 bucket: edge -> bucket[dst>>5] append {(rel*32+row)<<17|src, val}
//              (1563 buckets, cap 1024, avg 512; overflow -> spill list).
//   K3 fused:  block = 32 dst rows. Build 256-key LDS mini-CSR (count/scan/
//              place) over its bucket, then per relation: gather agg rows
//              into LDS (f32 regs -> bf16), MFMA-accumulate, out f32 once.
//   K4 spill:  f32 GEMV + atomic for overflow edges (normally zero).
// N=50000, R=8, E=100000, IN=OUT=128.

constexpr int IN    = 128;
constexpr int OUT   = 128;
constexpr int BROWS = 32;    // dst rows per bucket/block
constexpr int LDK   = 136;   // padded LDS row (bf16) = 272 B
constexpr int NKEYS = 256;   // n_rel(<=8) * BROWS
constexpr int CAPMX = 1024;  // LDS edge-list capacity (= max bucket cap)
constexpr int SPILL_MAX = 65536;

typedef __attribute__((ext_vector_type(8))) short bf16x8;
typedef __attribute__((ext_vector_type(4))) float f32x4;

__device__ inline unsigned short f2bf(float f) {
    unsigned int u = __float_as_uint(f);
    u += 0x7fffu + ((u >> 16) & 1u);          // RNE
    return (unsigned short)(u >> 16);
}
__device__ inline float bflo(unsigned int u) { return __uint_as_float(u << 16); }
__device__ inline float bfhi(unsigned int u) { return __uint_as_float(u & 0xffff0000u); }

// ---------------- K1: conv inp + conv W + zero counters ---------------------
__global__ __launch_bounds__(256) void setup_kernel(
    const float* __restrict__ inp, const float* __restrict__ w,
    unsigned short* __restrict__ inpb, unsigned short* __restrict__ wt,
    int* __restrict__ bcnt, int n8, int wt_tot, int nzero)
{
    const int nb_inp = (n8 + 255) / 256;
    const int nb_w   = (wt_tot + 255) / 256;
    const int b = blockIdx.x;
    const int tid = threadIdx.x;
    if (b < nb_inp) {
        const int i = b * 256 + tid;
        if (i < n8) {
            const float4 a = ((const float4*)inp)[i * 2];
            const float4 c = ((const float4*)inp)[i * 2 + 1];
            uint4 o;
            o.x = (unsigned)f2bf(a.x) | ((unsigned)f2bf(a.y) << 16);
            o.y = (unsigned)f2bf(a.z) | ((unsigned)f2bf(a.w) << 16);
            o.z = (unsigned)f2bf(c.x) | ((unsigned)f2bf(c.y) << 16);
            o.w = (unsigned)f2bf(c.z) | ((unsigned)f2bf(c.w) << 16);
            ((uint4*)inpb)[i] = o;
        }
    } else if (b < nb_inp + nb_w) {
        const int t = (b - nb_inp) * 256 + tid;
        if (t < wt_tot) {
            const int r = t >> 14, rem = t & 16383;
            const int n = rem >> 7, k = rem & 127;
            wt[t] = f2bf(w[(r << 14) + (k << 7) + n]);   // Wt[r][n][k]
        }
    } else {
        const int i = (b - nb_inp - nb_w) * 256 + tid;
        if (i < nzero) bcnt[i] = 0;
    }
}

// ---------------- K2: bucket fill -------------------------------------------
// bcnt[nbuckets] counters; bcnt[nbuckets] = spill counter.
__global__ __launch_bounds__(256) void bucket_fill(
    const int* __restrict__ src, const int* __restrict__ dst,
    const float* __restrict__ vals, int* __restrict__ bcnt,
    int2* __restrict__ bucket, int4* __restrict__ spill,
    int n_edges, int cap, int nbuckets)
{
    const int e = blockIdx.x * 256 + threadIdx.x;
    if (e >= n_edges) return;
    const int rel = blockIdx.y;
    const size_t g = (size_t)rel * n_edges + e;
    const int d = dst[g], s = src[g];
    const int vb = __float_as_int(vals[g]);
    const int bkt = d >> 5;                        // BROWS = 32
    const int enc = ((rel * BROWS + (d & 31)) << 17) | s;
    const int pos = atomicAdd(&bcnt[bkt], 1);
    if (pos < cap) {
        bucket[(size_t)bkt * cap + pos] = make_int2(enc, vb);
    } else {
        const int sp = atomicAdd(&bcnt[nbuckets], 1);
        if (sp < SPILL_MAX) spill[sp] = make_int4(d, s, vb, rel);
    }
}

// ---------------- K3: fused mini-CSR + aggregate + GEMM ---------------------
__global__ __launch_bounds__(256) void fused_kernel(
    const unsigned short* __restrict__ inpb,
    const unsigned short* __restrict__ wt,
    const int2* __restrict__ bucket, const int* __restrict__ bcnt,
    float* __restrict__ out, int n_nodes, int n_rel, int cap)
{
    __shared__ int2 elist[CAPMX];                 // 8 KB
    __shared__ unsigned short perm[CAPMX];        // 2 KB
    __shared__ int rcnt[NKEYS];                   // 1 KB (counts, kept)
    __shared__ int base[NKEYS];                   // 1 KB (excl. offsets)
    __shared__ int rcur[NKEYS];                   // 1 KB (placement cursor)
    __shared__ int ps[256];                       // 1 KB scan temp
    __shared__ unsigned short As[BROWS * LDK];    // 8.5 KB

    const int bkt = blockIdx.x;
    const int tid = threadIdx.x;
    int cnt = bcnt[bkt];
    if (cnt > cap) cnt = cap;

    // ---- mini-CSR over 256 keys (rel*32+row) ----
    rcnt[tid] = 0;
    __syncthreads();
    for (int j = tid; j < cnt; j += 256) {
        const int2 rec = bucket[(size_t)bkt * cap + j];
        elist[j] = rec;
        atomicAdd(&rcnt[rec.x >> 17], 1);
    }
    __syncthreads();
    const int myc = rcnt[tid];
    ps[tid] = myc;
    __syncthreads();
    #pragma unroll
    for (int d = 1; d < 256; d <<= 1) {
        const int v = (tid >= d) ? ps[tid - d] : 0;
        __syncthreads();
        ps[tid] += v;
        __syncthreads();
    }
    base[tid] = ps[tid] - myc;
    rcur[tid] = ps[tid] - myc;
    __syncthreads();
    for (int j = tid; j < cnt; j += 256) {
        const int key = elist[j].x >> 17;
        const int pos = atomicAdd(&rcur[key], 1);
        perm[pos] = (unsigned short)j;
    }
    // (rel-loop top barrier covers pass2 -> staging reads)

    const int row0 = bkt * BROWS;
    const int wave = tid >> 6, lane = tid & 63;
    const int m = lane & 15, q = lane >> 4;
    const int srow = tid >> 3, oct = tid & 7;     // staging: 8 thr/row

    f32x4 acc[2][2];
    #pragma unroll
    for (int mt = 0; mt < 2; ++mt)
        #pragma unroll
        for (int nt = 0; nt < 2; ++nt)
            acc[mt][nt] = (f32x4){0.f, 0.f, 0.f, 0.f};

    for (int r = 0; r < n_rel; ++r) {
        __syncthreads();   // As reuse + perm visibility

        // ---- stage: agg rows for relation r into As ----
        float accs[16];
        #pragma unroll
        for (int i = 0; i < 16; ++i) accs[i] = 0.f;
        {
            const int key = r * BROWS + srow;
            const int b0 = base[key], c0 = rcnt[key];
            for (int jj = 0; jj < c0; ++jj) {
                const int2 rec = elist[perm[b0 + jj]];
                const float v = __int_as_float(rec.y);
                const uint4* gp = (const uint4*)(
                    inpb + (size_t)(rec.x & 0x1FFFF) * IN + oct * 16);
                const uint4 u0 = gp[0], u1 = gp[1];
                accs[0] += v * bflo(u0.x);  accs[1] += v * bfhi(u0.x);
                accs[2] += v * bflo(u0.y);  accs[3] += v * bfhi(u0.y);
                accs[4] += v * bflo(u0.z);  accs[5] += v * bfhi(u0.z);
                accs[6] += v * bflo(u0.w);  accs[7] += v * bfhi(u0.w);
                accs[8] += v * bflo(u1.x);  accs[9] += v * bfhi(u1.x);
                accs[10] += v * bflo(u1.y); accs[11] += v * bfhi(u1.y);
                accs[12] += v * bflo(u1.z); accs[13] += v * bfhi(u1.z);
                accs[14] += v * bflo(u1.w); accs[15] += v * bfhi(u1.w);
            }
        }
        {
            unsigned int* lp = (unsigned int*)&As[srow * LDK + oct * 16];
            #pragma unroll
            for (int i = 0; i < 8; ++i)
                lp[i] = (unsigned)f2bf(accs[2 * i])
                      | ((unsigned)f2bf(accs[2 * i + 1]) << 16);
        }

        // ---- B fragments for this relation (L2-hot wt) ----
        bf16x8 bfrag[2][4];
        {
            const unsigned short* wtr =
                wt + ((size_t)r * OUT + wave * 32) * IN;
            #pragma unroll
            for (int nt = 0; nt < 2; ++nt)
                #pragma unroll
                for (int ks = 0; ks < 4; ++ks)
                    bfrag[nt][ks] = *(const bf16x8*)(
                        wtr + (size_t)(nt * 16 + m) * IN + ks * 32 + q * 8);
        }
        __syncthreads();

        // ---- MFMA: 2 M-tiles x 2 N-tiles, K=128 ----
        #pragma unroll
        for (int ks = 0; ks < 4; ++ks) {
            bf16x8 a[2];
            #pragma unroll
            for (int mt = 0; mt < 2; ++mt)
                a[mt] = *(const bf16x8*)&As[(mt * 16 + m) * LDK + ks * 32 + q * 8];
            #pragma unroll
            for (int mt = 0; mt < 2; ++mt) {
                acc[mt][0] = __builtin_amdgcn_mfma_f32_16x16x32_bf16(
                    a[mt], bfrag[0][ks], acc[mt][0], 0, 0, 0);
                acc[mt][1] = __builtin_amdgcn_mfma_f32_16x16x32_bf16(
                    a[mt], bfrag[1][ks], acc[mt][1], 0, 0, 0);
            }
        }
    }

    // ---- store: C/D lane holds rows q*4+0..3, col = nt*16 + m ----
    #pragma unroll
    for (int mt = 0; mt < 2; ++mt) {
        #pragma unroll
        for (int rg = 0; rg < 4; ++rg) {
            const int row = row0 + mt * 16 + q * 4 + rg;
            if (row < n_nodes) {
                float* op = out + (size_t)row * OUT + wave * 32 + m;
                op[0]  = acc[mt][0][rg];
                op[16] = acc[mt][1][rg];
            }
        }
    }
}

// ---------------- K4: spill cleanup (f32 GEMV + atomic; normally 0) ---------
__global__ __launch_bounds__(256) void spill_kernel(
    const float* __restrict__ inp, const float* __restrict__ weights,
    const int4* __restrict__ spill, const int* __restrict__ spill_cnt,
    float* __restrict__ out)
{
    int n = *spill_cnt;
    if (n > SPILL_MAX) n = SPILL_MAX;
    const int w = (blockIdx.x * 256 + threadIdx.x) >> 6;
    const int lane = threadIdx.x & 63;
    const int nw = gridDim.x * 4;
    for (int i = w; i < n; i += nw) {
        const int4 rec = spill[i];
        const float v = __int_as_float(rec.z);
        const float* __restrict__ arow = inp + (size_t)rec.y * IN;
        const float* __restrict__ W = weights + (size_t)rec.w * IN * OUT;
        float a0 = 0.f, a1 = 0.f;
        for (int k = 0; k < IN; ++k) {
            const float av = arow[k];
            a0 = fmaf(av, W[k * OUT + lane], a0);
            a1 = fmaf(av, W[k * OUT + lane + 64], a1);
        }
        float* orow = out + (size_t)rec.x * OUT;
        __hip_atomic_fetch_add(orow + lane, v * a0, __ATOMIC_RELAXED,
                               __HIP_MEMORY_SCOPE_AGENT);
        __hip_atomic_fetch_add(orow + lane + 64, v * a1, __ATOMIC_RELAXED,
                               __HIP_MEMORY_SCOPE_AGENT);
    }
}

// ---------------- last resort: per-edge GEMV scatter (no workspace) ---------
__global__ __launch_bounds__(256) void gemv_scatter_kernel(
    const float* __restrict__ inp, const float* __restrict__ weights,
    const int* __restrict__ src, const int* __restrict__ dst,
    const float* __restrict__ vals, float* __restrict__ out, int n_edges)
{
    const int e = blockIdx.x * 4 + (threadIdx.x >> 6);
    if (e >= n_edges) return;
    const int lane = threadIdx.x & 63;
    const int r = blockIdx.y;
    const size_t g = (size_t)r * n_edges + e;
    const int s = src[g], d = dst[g];
    const float v = vals[g];
    const float* __restrict__ arow = inp + (size_t)s * IN;
    const float* __restrict__ W = weights + (size_t)r * IN * OUT;
    float a0 = 0.f, a1 = 0.f;
    for (int k = 0; k < IN; ++k) {
        const float av = arow[k];
        a0 = fmaf(av, W[k * OUT + lane], a0);
        a1 = fmaf(av, W[k * OUT + lane + 64], a1);
    }
    float* orow = out + (size_t)d * OUT;
    __hip_atomic_fetch_add(orow + lane, v * a0, __ATOMIC_RELAXED,
                           __HIP_MEMORY_SCOPE_AGENT);
    __hip_atomic_fetch_add(orow + lane + 64, v * a1, __ATOMIC_RELAXED,
                           __HIP_MEMORY_SCOPE_AGENT);
}

extern "C" void kernel_launch(void* const* d_in, const int* in_sizes, int n_in,
                              void* d_out, int out_size, void* d_ws, size_t ws_size,
                              hipStream_t stream) {
    const float* inp     = (const float*)d_in[0];
    const int*   src     = (const int*)  d_in[1];
    const int*   dst     = (const int*)  d_in[2];
    const float* vals    = (const float*)d_in[3];
    const float* weights = (const float*)d_in[4];
    float* out = (float*)d_out;

    const int n_nodes = in_sizes[0] / IN;            // 50000
    const int n_rel   = in_sizes[4] / (IN * OUT);    // 8
    const int n_edges = in_sizes[1] / n_rel;         // 100000

    auto align_up = [](size_t x) { return (x + 255) & ~(size_t)255; };
    const int nbuckets = (n_nodes + BROWS - 1) / BROWS;
    const size_t sz_inpb = align_up((size_t)n_nodes * IN * 2);
    const size_t sz_wt   = align_up((size_t)n_rel * IN * OUT * 2);
    const size_t sz_bcnt = align_up((size_t)(nbuckets + 1) * 4);
    const size_t sz_spill = align_up((size_t)SPILL_MAX * 16);

    const int n8 = n_nodes * IN / 8;
    const int wt_tot = n_rel * IN * OUT;

    if (n_rel * BROWS <= NKEYS && n_nodes < (1 << 17)) {
        // pick bucket capacity that fits ws
        int cap = 0;
        const int caps[] = {CAPMX, 512, 256};
        for (int c : caps) {
            const size_t need = sz_inpb + sz_wt + sz_bcnt + sz_spill
                              + align_up((size_t)nbuckets * c * 8);
            if (need <= ws_size) { cap = c; break; }
        }
        if (cap > 0) {
            char* p = (char*)d_ws;
            unsigned short* inpb = (unsigned short*)p;  p += sz_inpb;
            unsigned short* wtb  = (unsigned short*)p;  p += sz_wt;
            int*  bcnt  = (int*)p;   p += sz_bcnt;
            int4* spill = (int4*)p;  p += sz_spill;
            int2* bucket = (int2*)p;

            const int nb_inp = (n8 + 255) / 256;
            const int nb_w   = (wt_tot + 255) / 256;
            const int nb_z   = (nbuckets + 1 + 255) / 256;
            setup_kernel<<<nb_inp + nb_w + nb_z, 256, 0, stream>>>(
                inp, weights, inpb, wtb, bcnt, n8, wt_tot, nbuckets + 1);

            dim3 fg((n_edges + 255) / 256, n_rel);
            bucket_fill<<<fg, 256, 0, stream>>>(src, dst, vals, bcnt, bucket,
                                                spill, n_edges, cap, nbuckets);

            fused_kernel<<<nbuckets, 256, 0, stream>>>(
                inpb, wtb, bucket, bcnt, out, n_nodes, n_rel, cap);

            spill_kernel<<<64, 256, 0, stream>>>(inp, weights, spill,
                                                 bcnt + nbuckets, out);
            return;
        }
    }

    // last resort: no workspace needed
    hipMemsetAsync(out, 0, (size_t)n_nodes * OUT * 4, stream);
    dim3 g((n_edges + 3) / 4, n_rel);
    gemv_scatter_kernel<<<g, 256, 0, stream>>>(inp, weights, src, dst, vals,
                                               out, n_edges);
}